// Round 3
// baseline (2241.533 us; speedup 1.0000x reference)
//
#include <hip/hip_runtime.h>

typedef unsigned short ushort_t;
typedef __bf16 bf16x8 __attribute__((ext_vector_type(8)));
typedef float f32x4 __attribute__((ext_vector_type(4)));

#define PACK_W_ELEMS (64*9*512)            // 294912 bf16 per LSTM (64 n-tiles x 9 k-tiles x 512)
#define HEAD_ELEMS   (9*512)               // 1 n-tile x 9 k-tiles
#define PACK_TOTAL   (4*PACK_W_ELEMS + 2*HEAD_ELEMS)
#define FLAG_OFS     PACK_TOTAL            // ushort index of int dtype flag (4B aligned)

__device__ __forceinline__ float bf2f(ushort_t u){ return __uint_as_float(((unsigned)u)<<16); }
__device__ __forceinline__ ushort_t f2bf(float f){
  unsigned u = __float_as_uint(f);
  if ((u & 0x7fffffffu) > 0x7f800000u) return (ushort_t)0x7fc0;  // NaN guard
  u += 0x7fffu + ((u>>16)&1u);      // round-to-nearest-even
  return (ushort_t)(u>>16);
}
__device__ __forceinline__ float sigmf_(float x){ return 1.0f/(1.0f + __expf(-x)); }
__device__ __forceinline__ float tanhf_(float x){ return 1.0f - 2.0f/(1.0f + __expf(2.0f*x)); }

// dtype sniff: bf16 arrays have EVERY ushort a plausible small bf16; fp32 arrays have
// mantissa-random even ushorts (P(all 32 probes in (-8,8)) ~ 4e-10).
__device__ __forceinline__ int sniff_f32(const ushort_t* w){
  int f32 = 0;
  #pragma unroll
  for (int i = 0; i < 32; ++i){
    float f = bf2f(w[2*i]);
    if (!(f > -8.f && f < 8.f)) f32 = 1;
  }
  return f32;
}
__device__ __forceinline__ float ldin(const ushort_t* p, int i, int f32){
  return f32 ? ((const float*)p)[i] : bf2f(p[i]);
}
__device__ __forceinline__ ushort_t ldw(const ushort_t* p, int i, int f32){
  return f32 ? f2bf(((const float*)p)[i]) : p[i];
}

// ---------------- pack kernel: weights -> MFMA B-fragment layout in ws ----------------
// Per-LSTM pack, K=288 (9 k-tiles of 32): k<256 = Whh cols, k=256..259 = Wih cols,
// k==260 = bias row (bih+bhh, paired with constant-1.0 A column), k>260 = 0.
// Head packs (1 n-tile x 9 kt): speed = fc_speed rows 0..3 + bias row; cross = emb rows
// 0..3 + fc_cross rows 4..5 + bias row.
struct PackArgs {
  const ushort_t* wih[4]; const ushort_t* whh[4];
  const ushort_t* bih[4]; const ushort_t* bhh[4];
  const ushort_t* fcsp_w; const ushort_t* fcsp_b;
  const ushort_t* fccr_w; const ushort_t* fccr_b;
  const ushort_t* emb_w;  const ushort_t* emb_b;
  ushort_t* ws;
};

__global__ void pack_kernel(PackArgs a){
  const int f32 = sniff_f32(a.whh[0]);
  int idx = blockIdx.x*256 + threadIdx.x;
  if (blockIdx.x == 0 && threadIdx.x == 0) *(int*)(a.ws + FLAG_OFS) = f32;
  const int total_w = 4*PACK_W_ELEMS;
  if (idx < total_w){
    int l = idx / PACK_W_ELEMS;
    int r = idx % PACK_W_ELEMS;
    int j = r & 7;
    int lane = (r>>3) & 63;
    int tile = r >> 9;            // ntg*9 + kt
    int kt = tile % 9;
    int ntg = tile / 9;
    int n = ntg*16 + (lane & 15);
    int k = kt*32 + ((lane>>4)<<3) + j;
    ushort_t v = 0;
    if (k < 256)       v = ldw(a.whh[l], n*256 + k, f32);
    else if (k < 260)  v = ldw(a.wih[l], n*4 + (k-256), f32);
    else if (k == 260) v = f2bf(ldin(a.bih[l], n, f32) + ldin(a.bhh[l], n, f32));
    a.ws[l*PACK_W_ELEMS + r] = v;
    return;
  }
  idx -= total_w;
  if (idx < 2*HEAD_ELEMS){
    int which = idx / HEAD_ELEMS;           // 0 = speed, 1 = cross
    int r = idx % HEAD_ELEMS;
    int j = r & 7; int lane = (r>>3)&63; int kt = r>>9;
    int n = lane & 15; int k = kt*32 + ((lane>>4)<<3) + j;
    ushort_t v = 0;
    if (which == 0){
      if (n < 4){
        if (k < 256)       v = ldw(a.fcsp_w, n*256 + k, f32);
        else if (k == 260) v = f2bf(ldin(a.fcsp_b, n, f32));
      }
    } else {
      if (n < 4){
        if (k < 256)       v = ldw(a.emb_w, n*256 + k, f32);
        else if (k == 260) v = f2bf(ldin(a.emb_b, n, f32));
      } else if (n < 6){
        if (k < 256)       v = ldw(a.fccr_w, (n-4)*256 + k, f32);
        else if (k == 260) v = f2bf(ldin(a.fccr_b, n-4, f32));
      }
    }
    a.ws[total_w + idx] = v;
  }
}

// ---------------- main kernel: 256 blocks x 64 batch rows, all 4 phases ----------------
// Wave w (of 8) owns h-cols [w*32, w*32+32) for all 4 gates and all 4 m-tiles:
// n-tiles ntg = g*16 + w*2 + u (g in 0..3, u in 0..1). Every B tile is loaded by
// exactly one wave per CU (no redundancy). acc[4][8] f32x4 = 128 AGPRs.
__global__ __launch_bounds__(512, 2) void pvlstm_main(
    const ushort_t* __restrict__ ws,
    const ushort_t* __restrict__ speed,
    const ushort_t* __restrict__ pos,
    void* __restrict__ outv)
{
  __shared__ ushort_t Ap[4*9*512];    // A-pack, MFMA A-frag order (36 KB)
  __shared__ ushort_t h0s[64*256];    // h0 = h_sp + h_po (bf16, 32 KB)
  __shared__ float    c0s[64*256];    // c0 = c_sp + c_po (fp32, 64 KB)
  __shared__ ushort_t xs[64*64];      // staged x for current phase (bf16, 8 KB)
  __shared__ float    ost[64*64];     // output stage for decoder phases (16 KB)

  const int f32   = *(const int*)(ws + FLAG_OFS);
  const int tid   = threadIdx.x;
  const int lane  = tid & 63;
  const int w     = tid >> 6;   // 0..7  (n-slice owner)
  const int col16 = lane & 15;
  const int quad  = lane >> 4;
  const int brow0 = blockIdx.x * 64;

  ushort_t* outu = (ushort_t*)outv;
  float*    outf = (float*)outv;

  const ushort_t* headsp = ws + 4*PACK_W_ELEMS;
  const ushort_t* headcr = headsp + HEAD_ELEMS;

  const f32x4 zero4 = {0.f, 0.f, 0.f, 0.f};
  float cw[4][2][4];   // cell state (C-layout per lane)

  for (int phase = 0; phase < 4; ++phase){
    const ushort_t* packW = ws + phase*PACK_W_ELEMS;
    const ushort_t* seq = (phase & 1) ? pos : speed;  // 0:sp 1:po 2:sp 3:po
    const bool is_enc = (phase < 2);
    const ushort_t* headW = (phase == 2) ? headsp : headcr;

    __syncthreads();
    // stage x for the whole phase (once): xs[row][0..63] bf16
    for (int i = tid; i < 4096; i += 512)
      xs[i] = f2bf(ldin(seq, (brow0 + (i>>6))*64 + (i&63), f32));

    if (is_enc){
      // h := 0 (zero whole A-pack; pads stay zero)
      for (int i = tid; i < 4*9*512/2; i += 512) ((unsigned*)Ap)[i] = 0u;
      #pragma unroll
      for (int mt = 0; mt < 4; ++mt)
        #pragma unroll
        for (int u = 0; u < 2; ++u)
          #pragma unroll
          for (int r = 0; r < 4; ++r) cw[mt][u][r] = 0.f;
    } else {
      // h := h0 (bf16 copy into A-frag layout), c := c0
      for (int i = tid; i < 64*256; i += 512){
        int m = i >> 8, col = i & 255;
        Ap[((m>>4)*9 + (col>>5))*512 + ((col>>3)&3)*128 + (m&15)*8 + (col&7)] = h0s[i];
      }
      #pragma unroll
      for (int mt = 0; mt < 4; ++mt)
        #pragma unroll
        for (int u = 0; u < 2; ++u)
          #pragma unroll
          for (int r = 0; r < 4; ++r)
            cw[mt][u][r] = c0s[(mt*16 + quad*4 + r)*256 + w*32 + u*16 + col16];
    }
    __syncthreads();
    if (tid < 64){
      // kt=8 tile of row m=tid: j0..3 = x (decoder: x0), j4 = 1.0 (bias column), j5..7 = 0
      ushort_t* xp = &Ap[((tid>>4)*9 + 8)*512 + (tid&15)*8];
      if (!is_enc) *(uint2*)xp = *(const uint2*)&xs[tid*64 + 60];
      xp[4] = (ushort_t)0x3f80; xp[5] = 0; xp[6] = 0; xp[7] = 0;
    }
    __syncthreads();

    const ushort_t* bbase = packW + ((size_t)(w*2)*9)*512 + (size_t)lane*8;

    for (int t = 0; t < 16; ++t){
      if (is_enc){
        if (tid < 64)
          *(uint2*)&Ap[((tid>>4)*9 + 8)*512 + (tid&15)*8] = *(const uint2*)&xs[tid*64 + t*4];
        __syncthreads();
      }

      // ---- gate GEMM: [64,288+bias] x [288,1024]; wave covers 4 m-tiles x 8 n-tiles ----
      f32x4 acc[4][8];
      #pragma unroll
      for (int i = 0; i < 4; ++i)
        #pragma unroll
        for (int j = 0; j < 8; ++j) acc[i][j] = zero4;

      #pragma unroll 3
      for (int kt = 0; kt < 9; ++kt){
        bf16x8 a[4];
        #pragma unroll
        for (int mt = 0; mt < 4; ++mt)
          a[mt] = *(const bf16x8*)&Ap[(mt*9+kt)*512 + lane*8];
        #pragma unroll
        for (int g = 0; g < 4; ++g){
          #pragma unroll
          for (int u = 0; u < 2; ++u){
            bf16x8 bv = *(const bf16x8*)&bbase[((size_t)((g*16+u)*9 + kt))*512];
            #pragma unroll
            for (int mt = 0; mt < 4; ++mt)
              acc[mt][g*2+u] = __builtin_amdgcn_mfma_f32_16x16x32_bf16(a[mt], bv, acc[mt][g*2+u], 0, 0, 0);
          }
        }
      }
      __syncthreads();   // all A reads done; safe to overwrite h

      // ---- gate nonlinearity + state update (gates share C-layout in-lane) ----
      const bool enc_last = is_enc && (t == 15);
      #pragma unroll
      for (int mt = 0; mt < 4; ++mt){
        #pragma unroll
        for (int u = 0; u < 2; ++u){
          const int col = w*32 + u*16 + col16;
          #pragma unroll
          for (int r = 0; r < 4; ++r){
            float gi = acc[mt][0+u][r];
            float gf = acc[mt][2+u][r];
            float gg = acc[mt][4+u][r];
            float go = acc[mt][6+u][r];
            float cn = sigmf_(gf)*cw[mt][u][r] + sigmf_(gi)*tanhf_(gg);
            float hn = sigmf_(go)*tanhf_(cn);
            cw[mt][u][r] = cn;
            const int m = mt*16 + quad*4 + r;
            if (enc_last){
              if (phase == 0){ h0s[m*256+col] = f2bf(hn);  c0s[m*256+col] = cn; }
              else { h0s[m*256+col] = f2bf(bf2f(h0s[m*256+col]) + hn);  c0s[m*256+col] += cn; }
            } else {
              Ap[(mt*9 + (col>>5))*512 + ((col>>3)&3)*128 + (m&15)*8 + (col&7)] = f2bf(hn);
            }
          }
        }
      }

      if (!is_enc){
        __syncthreads();   // h_t visible for head
        if (w < 4){        // wave w handles m-tile w; kt=8 folds x(zero rows)+bias
          f32x4 hacc = zero4;
          #pragma unroll
          for (int kt = 0; kt < 9; ++kt){
            bf16x8 a  = *(const bf16x8*)&Ap[(w*9+kt)*512 + lane*8];
            bf16x8 bv = *(const bf16x8*)&headW[((size_t)kt*64 + lane)*8];
            hacc = __builtin_amdgcn_mfma_f32_16x16x32_bf16(a, bv, hacc, 0, 0, 0);
          }
          const int s = col16;
          if (phase == 2){
            if (s < 4){
              #pragma unroll
              for (int r = 0; r < 4; ++r){
                float v = fminf(fmaxf(hacc[r], -100.f), 100.f);   // hardtanh(+-100)
                const int m = w*16 + quad*4 + r;
                ost[m*64 + t*4 + s] = v;                           // staged speed output
                Ap[(w*9+8)*512 + (m&15)*8 + s] = f2bf(v);          // feedback x_{t+1}
              }
            }
          } else {
            #pragma unroll
            for (int r = 0; r < 4; ++r){
              float v = fmaxf(hacc[r], 0.f);          // relu
              const float o = __shfl_xor(v, 1, 64);   // pair lanes 4<->5 (logits)
              const int m = w*16 + quad*4 + r;
              if (s < 4){
                Ap[(w*9+8)*512 + (m&15)*8 + s] = f2bf(v);          // feedback relu(emb)
              } else if (s < 6){
                const float mx = fmaxf(v, o);
                const float e0 = __expf(v-mx), e1 = __expf(o-mx);
                ost[m*32 + t*2 + (s-4)] = e0/(e0+e1);              // staged softmax2
              }
            }
          }
        }
        __syncthreads();   // feedback x + ost visible
      }
    }

    // ---- coalesced output flush at decoder phase end ----
    if (phase == 2){
      for (int i = tid; i < 4096; i += 512){
        const int oi = (brow0 + (i>>6))*64 + (i&63);
        const float v = ost[i];
        if (f32) outf[oi] = v; else outu[oi] = f2bf(v);
      }
    } else if (phase == 3){
      for (int i = tid; i < 2048; i += 512){
        const int oi = 1048576 + (brow0 + (i>>5))*32 + (i&31);
        const float v = ost[i];
        if (f32) outf[oi] = v; else outu[oi] = f2bf(v);
      }
    }
  }
}

extern "C" void kernel_launch(void* const* d_in, const int* in_sizes, int n_in,
                              void* d_out, int out_size, void* d_ws, size_t ws_size,
                              hipStream_t stream) {
  PackArgs pa;
  pa.wih[0]=(const ushort_t*)d_in[2];  pa.whh[0]=(const ushort_t*)d_in[3];
  pa.bih[0]=(const ushort_t*)d_in[4];  pa.bhh[0]=(const ushort_t*)d_in[5];
  pa.wih[1]=(const ushort_t*)d_in[6];  pa.whh[1]=(const ushort_t*)d_in[7];
  pa.bih[1]=(const ushort_t*)d_in[8];  pa.bhh[1]=(const ushort_t*)d_in[9];
  pa.wih[2]=(const ushort_t*)d_in[10]; pa.whh[2]=(const ushort_t*)d_in[11];
  pa.bih[2]=(const ushort_t*)d_in[12]; pa.bhh[2]=(const ushort_t*)d_in[13];
  pa.wih[3]=(const ushort_t*)d_in[14]; pa.whh[3]=(const ushort_t*)d_in[15];
  pa.bih[3]=(const ushort_t*)d_in[16]; pa.bhh[3]=(const ushort_t*)d_in[17];
  pa.fcsp_w=(const ushort_t*)d_in[18]; pa.fcsp_b=(const ushort_t*)d_in[19];
  pa.fccr_w=(const ushort_t*)d_in[20]; pa.fccr_b=(const ushort_t*)d_in[21];
  pa.emb_w =(const ushort_t*)d_in[22]; pa.emb_b =(const ushort_t*)d_in[23];
  pa.ws = (ushort_t*)d_ws;

  hipLaunchKernelGGL(pack_kernel, dim3((PACK_TOTAL + 255)/256), dim3(256), 0, stream, pa);
  hipLaunchKernelGGL(pvlstm_main, dim3(256), dim3(512), 0, stream,
      (const ushort_t*)d_ws,
      (const ushort_t*)d_in[0], (const ushort_t*)d_in[1],
      d_out);
}

// Round 4
// 1264.460 us; speedup vs baseline: 1.7727x; 1.7727x over previous
//
#include <hip/hip_runtime.h>

typedef unsigned short ushort_t;
typedef __bf16 bf16x8 __attribute__((ext_vector_type(8)));
typedef float f32x4 __attribute__((ext_vector_type(4)));

#define PACK_W_ELEMS (16*9*4*512)          // 294912 bf16 per LSTM: [wave16][kt9][gate4][512]
#define HEAD_ELEMS   (9*512)               // 1 n-tile x 9 k-tiles
#define PACK_TOTAL   (4*PACK_W_ELEMS + 2*HEAD_ELEMS)
#define FLAG_OFS     PACK_TOTAL            // ushort index of int dtype flag (4B aligned)

__device__ __forceinline__ float bf2f(ushort_t u){ return __uint_as_float(((unsigned)u)<<16); }
__device__ __forceinline__ ushort_t f2bf(float f){
  unsigned u = __float_as_uint(f);
  if ((u & 0x7fffffffu) > 0x7f800000u) return (ushort_t)0x7fc0;  // NaN guard
  u += 0x7fffu + ((u>>16)&1u);      // round-to-nearest-even
  return (ushort_t)(u>>16);
}
__device__ __forceinline__ float sigmf_(float x){ return 1.0f/(1.0f + __expf(-x)); }
__device__ __forceinline__ float tanhf_(float x){ return 1.0f - 2.0f/(1.0f + __expf(2.0f*x)); }

// dtype sniff: bf16 arrays have EVERY ushort a plausible small bf16; fp32 arrays have
// mantissa-random even ushorts (P(all 32 probes in (-8,8)) ~ 4e-10).
__device__ __forceinline__ int sniff_f32(const ushort_t* w){
  int f32 = 0;
  #pragma unroll
  for (int i = 0; i < 32; ++i){
    float f = bf2f(w[2*i]);
    if (!(f > -8.f && f < 8.f)) f32 = 1;
  }
  return f32;
}
__device__ __forceinline__ float ldin(const ushort_t* p, int i, int f32){
  return f32 ? ((const float*)p)[i] : bf2f(p[i]);
}
__device__ __forceinline__ ushort_t ldw(const ushort_t* p, int i, int f32){
  return f32 ? f2bf(((const float*)p)[i]) : p[i];
}

// ---------------- pack kernel: weights -> MFMA B-fragment layout in ws ----------------
// Per-LSTM pack, wave-contiguous: tile order [w(16)][kt(9)][g(4)], each tile 512 = 64 lanes x 8.
// Tile (w,kt,g) = B-fragment of n-tile ntg = g*16+w (gate g, cols [w*16,w*16+16)), k-tile kt.
// K map: k<256 = Whh cols, 256..259 = Wih cols, k==260 = bias row (bih+bhh; pairs with
// the constant-1.0 A column), else 0.
struct PackArgs {
  const ushort_t* wih[4]; const ushort_t* whh[4];
  const ushort_t* bih[4]; const ushort_t* bhh[4];
  const ushort_t* fcsp_w; const ushort_t* fcsp_b;
  const ushort_t* fccr_w; const ushort_t* fccr_b;
  const ushort_t* emb_w;  const ushort_t* emb_b;
  ushort_t* ws;
};

__global__ void pack_kernel(PackArgs a){
  const int f32 = sniff_f32(a.whh[0]);
  int idx = blockIdx.x*256 + threadIdx.x;
  if (blockIdx.x == 0 && threadIdx.x == 0) *(int*)(a.ws + FLAG_OFS) = f32;
  const int total_w = 4*PACK_W_ELEMS;
  if (idx < total_w){
    int l = idx / PACK_W_ELEMS;
    int r = idx % PACK_W_ELEMS;
    int j = r & 7;
    int lane = (r>>3) & 63;
    int tile = r >> 9;            // (wv*9 + kt)*4 + g
    int g  = tile & 3;
    int kt = (tile >> 2) % 9;
    int wv = tile / 36;
    int n = (g*16 + wv)*16 + (lane & 15);
    int k = kt*32 + ((lane>>4)<<3) + j;
    ushort_t v = 0;
    if (k < 256)       v = ldw(a.whh[l], n*256 + k, f32);
    else if (k < 260)  v = ldw(a.wih[l], n*4 + (k-256), f32);
    else if (k == 260) v = f2bf(ldin(a.bih[l], n, f32) + ldin(a.bhh[l], n, f32));
    a.ws[l*PACK_W_ELEMS + r] = v;
    return;
  }
  idx -= total_w;
  if (idx < 2*HEAD_ELEMS){
    int which = idx / HEAD_ELEMS;           // 0 = speed, 1 = cross
    int r = idx % HEAD_ELEMS;
    int j = r & 7; int lane = (r>>3)&63; int kt = r>>9;
    int n = lane & 15; int k = kt*32 + ((lane>>4)<<3) + j;
    ushort_t v = 0;
    if (which == 0){
      if (n < 4){
        if (k < 256)       v = ldw(a.fcsp_w, n*256 + k, f32);
        else if (k == 260) v = f2bf(ldin(a.fcsp_b, n, f32));
      }
    } else {
      if (n < 4){
        if (k < 256)       v = ldw(a.emb_w, n*256 + k, f32);
        else if (k == 260) v = f2bf(ldin(a.emb_b, n, f32));
      } else if (n < 6){
        if (k < 256)       v = ldw(a.fccr_w, (n-4)*256 + k, f32);
        else if (k == 260) v = f2bf(ldin(a.fccr_b, n-4, f32));
      }
    }
    a.ws[total_w + idx] = v;
  }
}

// ---------------- main kernel: 256 blocks x 64 rows, 1024 threads (16 waves) ----------------
// Wave w (0..15) owns h-cols [w*16, w*16+16) of all 4 gates and all 4 m-tiles:
// acc[4 mt][4 gates] f32x4 = 64 regs/thread. Every B tile loaded by exactly one wave per CU,
// per-wave B stream is contiguous (36 KB/step). Target <=128 regs -> 4 waves/SIMD.
__global__ __launch_bounds__(1024, 4) void pvlstm_main(
    const ushort_t* __restrict__ ws,
    const ushort_t* __restrict__ speed,
    const ushort_t* __restrict__ pos,
    void* __restrict__ outv)
{
  __shared__ ushort_t Ap[4*9*512];    // A-pack, MFMA A-frag order (36 KB)
  __shared__ ushort_t h0s[64*256];    // h0 = h_sp + h_po (bf16, 32 KB)
  __shared__ float    c0s[64*256];    // c0 = c_sp + c_po (fp32, 64 KB)
  __shared__ ushort_t xs[64*64];      // staged x for current phase (bf16, 8 KB)
  __shared__ float    ost[64*64];     // output stage for decoder phases (16 KB)

  const int f32   = *(const int*)(ws + FLAG_OFS);
  const int tid   = threadIdx.x;
  const int lane  = tid & 63;
  const int w     = tid >> 6;   // 0..15 (n-slice owner)
  const int col16 = lane & 15;
  const int quad  = lane >> 4;
  const int brow0 = blockIdx.x * 64;
  const int colw  = w*16 + col16;                 // this thread's h-column
  const int apw   = (colw>>5)*512 + ((colw>>3)&3)*128 + (colw&7);  // A-frag addr part

  ushort_t* outu = (ushort_t*)outv;
  float*    outf = (float*)outv;

  const ushort_t* headsp = ws + 4*PACK_W_ELEMS;
  const ushort_t* headcr = headsp + HEAD_ELEMS;

  const f32x4 zero4 = {0.f, 0.f, 0.f, 0.f};
  float cw[4][4];   // cell state [mt][r], col = colw

  for (int phase = 0; phase < 4; ++phase){
    const ushort_t* packW = ws + phase*PACK_W_ELEMS;
    const ushort_t* seq = (phase & 1) ? pos : speed;  // 0:sp 1:po 2:sp 3:po
    const bool is_enc = (phase < 2);
    const ushort_t* headW = (phase == 2) ? headsp : headcr;

    __syncthreads();
    // stage x for the whole phase: xs[row][0..63] bf16
    for (int i = tid; i < 4096; i += 1024)
      xs[i] = f2bf(ldin(seq, (brow0 + (i>>6))*64 + (i&63), f32));

    if (is_enc){
      for (int i = tid; i < 4*9*512/2; i += 1024) ((unsigned*)Ap)[i] = 0u;
      #pragma unroll
      for (int mt = 0; mt < 4; ++mt)
        #pragma unroll
        for (int r = 0; r < 4; ++r) cw[mt][r] = 0.f;
    } else {
      for (int i = tid; i < 64*256; i += 1024){
        int m = i >> 8, col = i & 255;
        Ap[((m>>4)*9 + (col>>5))*512 + ((col>>3)&3)*128 + (m&15)*8 + (col&7)] = h0s[i];
      }
      #pragma unroll
      for (int mt = 0; mt < 4; ++mt)
        #pragma unroll
        for (int r = 0; r < 4; ++r)
          cw[mt][r] = c0s[(mt*16 + quad*4 + r)*256 + colw];
    }
    __syncthreads();
    if (tid < 64){
      // kt=8 tile of row m=tid: j0..3 = x (decoder: x0), j4 = 1.0 (bias col), j5..7 = 0
      ushort_t* xp = &Ap[((tid>>4)*9 + 8)*512 + (tid&15)*8];
      if (!is_enc) *(uint2*)xp = *(const uint2*)&xs[tid*64 + 60];
      xp[4] = (ushort_t)0x3f80; xp[5] = 0; xp[6] = 0; xp[7] = 0;
    }
    __syncthreads();

    const ushort_t* bwave = packW + (size_t)w*(9*4*512) + (size_t)lane*8;

    for (int t = 0; t < 16; ++t){
      if (is_enc){
        if (tid < 64)
          *(uint2*)&Ap[((tid>>4)*9 + 8)*512 + (tid&15)*8] = *(const uint2*)&xs[tid*64 + t*4];
        __syncthreads();
      }

      // ---- gate GEMM: [64,288] x [288,1024]; wave covers 4 m-tiles x 4 gate-tiles ----
      f32x4 acc[4][4];
      #pragma unroll
      for (int i = 0; i < 4; ++i)
        #pragma unroll
        for (int j = 0; j < 4; ++j) acc[i][j] = zero4;

      const ushort_t* bp = bwave;
      #pragma unroll 1
      for (int kt = 0; kt < 9; ++kt){
        bf16x8 a0 = *(const bf16x8*)&Ap[(0*9+kt)*512 + lane*8];
        bf16x8 a1 = *(const bf16x8*)&Ap[(1*9+kt)*512 + lane*8];
        bf16x8 a2 = *(const bf16x8*)&Ap[(2*9+kt)*512 + lane*8];
        bf16x8 a3 = *(const bf16x8*)&Ap[(3*9+kt)*512 + lane*8];
        #pragma unroll
        for (int g = 0; g < 4; ++g){
          bf16x8 bv = *(const bf16x8*)&bp[g*512];
          acc[0][g] = __builtin_amdgcn_mfma_f32_16x16x32_bf16(a0, bv, acc[0][g], 0, 0, 0);
          acc[1][g] = __builtin_amdgcn_mfma_f32_16x16x32_bf16(a1, bv, acc[1][g], 0, 0, 0);
          acc[2][g] = __builtin_amdgcn_mfma_f32_16x16x32_bf16(a2, bv, acc[2][g], 0, 0, 0);
          acc[3][g] = __builtin_amdgcn_mfma_f32_16x16x32_bf16(a3, bv, acc[3][g], 0, 0, 0);
        }
        bp += 4*512;
      }
      __syncthreads();   // all A reads done; safe to overwrite h

      // ---- gate nonlinearity + state update (gates share C-layout in-lane) ----
      const bool enc_last = is_enc && (t == 15);
      #pragma unroll
      for (int mt = 0; mt < 4; ++mt){
        #pragma unroll
        for (int r = 0; r < 4; ++r){
          float gi = acc[mt][0][r];
          float gf = acc[mt][1][r];
          float gg = acc[mt][2][r];
          float go = acc[mt][3][r];
          float cn = sigmf_(gf)*cw[mt][r] + sigmf_(gi)*tanhf_(gg);
          float hn = sigmf_(go)*tanhf_(cn);
          cw[mt][r] = cn;
          const int m = mt*16 + quad*4 + r;
          if (enc_last){
            if (phase == 0){ h0s[m*256+colw] = f2bf(hn);  c0s[m*256+colw] = cn; }
            else { h0s[m*256+colw] = f2bf(bf2f(h0s[m*256+colw]) + hn);  c0s[m*256+colw] += cn; }
          } else {
            Ap[mt*(9*512) + apw + (m&15)*8] = f2bf(hn);
          }
        }
      }

      if (!is_enc){
        __syncthreads();   // h_t visible for head
        if (w < 4){        // wave w handles m-tile w; kt=8 folds bias (x rows are 0 in head B)
          f32x4 hacc = zero4;
          #pragma unroll
          for (int kt = 0; kt < 9; ++kt){
            bf16x8 a  = *(const bf16x8*)&Ap[(w*9+kt)*512 + lane*8];
            bf16x8 bv = *(const bf16x8*)&headW[((size_t)kt*64 + lane)*8];
            hacc = __builtin_amdgcn_mfma_f32_16x16x32_bf16(a, bv, hacc, 0, 0, 0);
          }
          const int s = col16;
          if (phase == 2){
            if (s < 4){
              #pragma unroll
              for (int r = 0; r < 4; ++r){
                float v = fminf(fmaxf(hacc[r], -100.f), 100.f);   // hardtanh(+-100)
                const int m = w*16 + quad*4 + r;
                ost[m*64 + t*4 + s] = v;                           // staged speed output
                Ap[(w*9+8)*512 + (m&15)*8 + s] = f2bf(v);          // feedback x_{t+1}
              }
            }
          } else {
            #pragma unroll
            for (int r = 0; r < 4; ++r){
              float v = fmaxf(hacc[r], 0.f);          // relu
              const float o = __shfl_xor(v, 1, 64);   // pair lanes 4<->5 (logits)
              const int m = w*16 + quad*4 + r;
              if (s < 4){
                Ap[(w*9+8)*512 + (m&15)*8 + s] = f2bf(v);          // feedback relu(emb)
              } else if (s < 6){
                const float mx = fmaxf(v, o);
                const float e0 = __expf(v-mx), e1 = __expf(o-mx);
                ost[m*32 + t*2 + (s-4)] = e0/(e0+e1);              // staged softmax2
              }
            }
          }
        }
        __syncthreads();   // feedback x + ost visible
      }
    }

    // ---- coalesced output flush at decoder phase end ----
    if (phase == 2){
      for (int i = tid; i < 4096; i += 1024){
        const int oi = (brow0 + (i>>6))*64 + (i&63);
        const float v = ost[i];
        if (f32) outf[oi] = v; else outu[oi] = f2bf(v);
      }
    } else if (phase == 3){
      for (int i = tid; i < 2048; i += 1024){
        const int oi = 1048576 + (brow0 + (i>>5))*32 + (i&31);
        const float v = ost[i];
        if (f32) outf[oi] = v; else outu[oi] = f2bf(v);
      }
    }
  }
}

extern "C" void kernel_launch(void* const* d_in, const int* in_sizes, int n_in,
                              void* d_out, int out_size, void* d_ws, size_t ws_size,
                              hipStream_t stream) {
  PackArgs pa;
  pa.wih[0]=(const ushort_t*)d_in[2];  pa.whh[0]=(const ushort_t*)d_in[3];
  pa.bih[0]=(const ushort_t*)d_in[4];  pa.bhh[0]=(const ushort_t*)d_in[5];
  pa.wih[1]=(const ushort_t*)d_in[6];  pa.whh[1]=(const ushort_t*)d_in[7];
  pa.bih[1]=(const ushort_t*)d_in[8];  pa.bhh[1]=(const ushort_t*)d_in[9];
  pa.wih[2]=(const ushort_t*)d_in[10]; pa.whh[2]=(const ushort_t*)d_in[11];
  pa.bih[2]=(const ushort_t*)d_in[12]; pa.bhh[2]=(const ushort_t*)d_in[13];
  pa.wih[3]=(const ushort_t*)d_in[14]; pa.whh[3]=(const ushort_t*)d_in[15];
  pa.bih[3]=(const ushort_t*)d_in[16]; pa.bhh[3]=(const ushort_t*)d_in[17];
  pa.fcsp_w=(const ushort_t*)d_in[18]; pa.fcsp_b=(const ushort_t*)d_in[19];
  pa.fccr_w=(const ushort_t*)d_in[20]; pa.fccr_b=(const ushort_t*)d_in[21];
  pa.emb_w =(const ushort_t*)d_in[22]; pa.emb_b =(const ushort_t*)d_in[23];
  pa.ws = (ushort_t*)d_ws;

  hipLaunchKernelGGL(pack_kernel, dim3((PACK_TOTAL + 255)/256), dim3(256), 0, stream, pa);
  hipLaunchKernelGGL(pvlstm_main, dim3(256), dim3(1024), 0, stream,
      (const ushort_t*)d_ws,
      (const ushort_t*)d_in[0], (const ushort_t*)d_in[1],
      d_out);
}

// Round 5
// 1007.077 us; speedup vs baseline: 2.2258x; 1.2556x over previous
//
#include <hip/hip_runtime.h>

typedef unsigned short ushort_t;
typedef __bf16 bf16x8 __attribute__((ext_vector_type(8)));
typedef float f32x4 __attribute__((ext_vector_type(4)));

#define PACK_W_ELEMS (16*9*4*512)          // 294912 bf16 per LSTM: [wave16][kt9][gate4][512]
#define HEAD_ELEMS   (9*512)               // 1 n-tile x 9 k-tiles
#define PACK_TOTAL   (4*PACK_W_ELEMS + 2*HEAD_ELEMS)
#define FLAG_OFS     PACK_TOTAL            // ushort index of int dtype flag (4B aligned)

__device__ __forceinline__ float bf2f(ushort_t u){ return __uint_as_float(((unsigned)u)<<16); }
__device__ __forceinline__ ushort_t f2bf(float f){
  __bf16 h = (__bf16)f;                    // HW RTNE convert (values bounded; no NaN path)
  return *(ushort_t*)&h;
}
__device__ __forceinline__ float rcp_(float x){ return __builtin_amdgcn_rcpf(x); }
// sigmoid/tanh via hw exp + hw rcp (v_exp_f32 / v_rcp_f32); specials safe:
// exp->inf => rcp->0 => tanh->1; exp->0 => rcp(1)=1.
__device__ __forceinline__ float sigmf_(float x){ return rcp_(1.0f + __expf(-x)); }
__device__ __forceinline__ float tanhf_(float x){ return 1.0f - 2.0f*rcp_(1.0f + __expf(2.0f*x)); }

// dtype sniff: bf16 arrays have EVERY ushort a plausible small bf16; fp32 arrays have
// mantissa-random even ushorts (P(all 32 probes in (-8,8)) ~ 4e-10).
__device__ __forceinline__ int sniff_f32(const ushort_t* w){
  int f32 = 0;
  #pragma unroll
  for (int i = 0; i < 32; ++i){
    float f = bf2f(w[2*i]);
    if (!(f > -8.f && f < 8.f)) f32 = 1;
  }
  return f32;
}
__device__ __forceinline__ float ldin(const ushort_t* p, int i, int f32){
  return f32 ? ((const float*)p)[i] : bf2f(p[i]);
}
__device__ __forceinline__ ushort_t ldw(const ushort_t* p, int i, int f32){
  return f32 ? f2bf(((const float*)p)[i]) : p[i];
}

// ---------------- pack kernel: weights -> MFMA B-fragment layout in ws ----------------
// Per-LSTM pack, wave-contiguous: tile order [w(16)][kt(9)][g(4)], each tile 512 = 64 lanes x 8.
// Tile (w,kt,g) = B-fragment of n-tile ntg = g*16+w (gate g, cols [w*16,w*16+16)), k-tile kt.
// K map: k<256 = Whh cols, 256..259 = Wih cols, k==260 = bias row (bih+bhh; pairs with
// the constant-1.0 A column), else 0.
struct PackArgs {
  const ushort_t* wih[4]; const ushort_t* whh[4];
  const ushort_t* bih[4]; const ushort_t* bhh[4];
  const ushort_t* fcsp_w; const ushort_t* fcsp_b;
  const ushort_t* fccr_w; const ushort_t* fccr_b;
  const ushort_t* emb_w;  const ushort_t* emb_b;
  ushort_t* ws;
};

__global__ void pack_kernel(PackArgs a){
  const int f32 = sniff_f32(a.whh[0]);
  int idx = blockIdx.x*256 + threadIdx.x;
  if (blockIdx.x == 0 && threadIdx.x == 0) *(int*)(a.ws + FLAG_OFS) = f32;
  const int total_w = 4*PACK_W_ELEMS;
  if (idx < total_w){
    int l = idx / PACK_W_ELEMS;
    int r = idx % PACK_W_ELEMS;
    int j = r & 7;
    int lane = (r>>3) & 63;
    int tile = r >> 9;            // (wv*9 + kt)*4 + g
    int g  = tile & 3;
    int kt = (tile >> 2) % 9;
    int wv = tile / 36;
    int n = (g*16 + wv)*16 + (lane & 15);
    int k = kt*32 + ((lane>>4)<<3) + j;
    ushort_t v = 0;
    if (k < 256)       v = ldw(a.whh[l], n*256 + k, f32);
    else if (k < 260)  v = ldw(a.wih[l], n*4 + (k-256), f32);
    else if (k == 260) v = f2bf(ldin(a.bih[l], n, f32) + ldin(a.bhh[l], n, f32));
    a.ws[l*PACK_W_ELEMS + r] = v;
    return;
  }
  idx -= total_w;
  if (idx < 2*HEAD_ELEMS){
    int which = idx / HEAD_ELEMS;           // 0 = speed, 1 = cross
    int r = idx % HEAD_ELEMS;
    int j = r & 7; int lane = (r>>3)&63; int kt = r>>9;
    int n = lane & 15; int k = kt*32 + ((lane>>4)<<3) + j;
    ushort_t v = 0;
    if (which == 0){
      if (n < 4){
        if (k < 256)       v = ldw(a.fcsp_w, n*256 + k, f32);
        else if (k == 260) v = f2bf(ldin(a.fcsp_b, n, f32));
      }
    } else {
      if (n < 4){
        if (k < 256)       v = ldw(a.emb_w, n*256 + k, f32);
        else if (k == 260) v = f2bf(ldin(a.emb_b, n, f32));
      } else if (n < 6){
        if (k < 256)       v = ldw(a.fccr_w, (n-4)*256 + k, f32);
        else if (k == 260) v = f2bf(ldin(a.fccr_b, n-4, f32));
      }
    }
    a.ws[total_w + idx] = v;
  }
}

// ---------------- main kernel: 256 blocks x 64 rows, 1024 threads (16 waves) ----------------
// Wave w (0..15) owns h-cols [w*16, w*16+16) of all 4 gates and all 4 m-tiles:
// acc[4 mt][4 gates] f32x4 = 64 regs/thread. Every B tile loaded by exactly one wave per CU,
// per-wave B stream is contiguous (36 KB/step). NOTE: 1024-thread blocks require 4 waves/SIMD
// co-resident -> hard cap 128 regs/thread; keep live state lean.
__global__ __launch_bounds__(1024, 4) void pvlstm_main(
    const ushort_t* __restrict__ ws,
    const ushort_t* __restrict__ speed,
    const ushort_t* __restrict__ pos,
    void* __restrict__ outv)
{
  __shared__ ushort_t Ap[4*9*512];    // A-pack, MFMA A-frag order (36 KB)
  __shared__ ushort_t h0s[64*256];    // h0 = h_sp + h_po (bf16, 32 KB)
  __shared__ float    c0s[64*256];    // c0 = c_sp + c_po (fp32, 64 KB)
  __shared__ ushort_t xs[64*64];      // staged x for current phase (bf16, 8 KB)
  __shared__ float    ost[64*64];     // output stage for decoder phases (16 KB)

  const int f32   = *(const int*)(ws + FLAG_OFS);
  const int tid   = threadIdx.x;
  const int lane  = tid & 63;
  const int w     = tid >> 6;   // 0..15 (n-slice owner)
  const int col16 = lane & 15;
  const int quad  = lane >> 4;
  const int brow0 = blockIdx.x * 64;
  const int colw  = w*16 + col16;                 // this thread's h-column
  const int apw   = (colw>>5)*512 + ((colw>>3)&3)*128 + (colw&7);  // A-frag addr part

  ushort_t* outu = (ushort_t*)outv;
  float*    outf = (float*)outv;

  const ushort_t* headsp = ws + 4*PACK_W_ELEMS;
  const ushort_t* headcr = headsp + HEAD_ELEMS;

  const f32x4 zero4 = {0.f, 0.f, 0.f, 0.f};
  float cw[4][4];   // cell state [mt][r], col = colw

  for (int phase = 0; phase < 4; ++phase){
    const ushort_t* packW = ws + phase*PACK_W_ELEMS;
    const ushort_t* seq = (phase & 1) ? pos : speed;  // 0:sp 1:po 2:sp 3:po
    const bool is_enc = (phase < 2);
    const ushort_t* headW = (phase == 2) ? headsp : headcr;

    __syncthreads();
    // stage x for the whole phase: xs[row][0..63] bf16
    for (int i = tid; i < 4096; i += 1024)
      xs[i] = f2bf(ldin(seq, (brow0 + (i>>6))*64 + (i&63), f32));

    if (is_enc){
      for (int i = tid; i < 4*9*512/2; i += 1024) ((unsigned*)Ap)[i] = 0u;
      #pragma unroll
      for (int mt = 0; mt < 4; ++mt)
        #pragma unroll
        for (int r = 0; r < 4; ++r) cw[mt][r] = 0.f;
    } else {
      for (int i = tid; i < 64*256; i += 1024){
        int m = i >> 8, col = i & 255;
        Ap[((m>>4)*9 + (col>>5))*512 + ((col>>3)&3)*128 + (m&15)*8 + (col&7)] = h0s[i];
      }
      #pragma unroll
      for (int mt = 0; mt < 4; ++mt)
        #pragma unroll
        for (int r = 0; r < 4; ++r)
          cw[mt][r] = c0s[(mt*16 + quad*4 + r)*256 + colw];
    }
    __syncthreads();
    if (tid < 64){
      // kt=8 tile of row m=tid: j0..3 = x (decoder: x0), j4 = 1.0 (bias col), j5..7 = 0
      ushort_t* xp = &Ap[((tid>>4)*9 + 8)*512 + (tid&15)*8];
      if (!is_enc) *(uint2*)xp = *(const uint2*)&xs[tid*64 + 60];
      xp[4] = (ushort_t)0x3f80; xp[5] = 0; xp[6] = 0; xp[7] = 0;
    }
    __syncthreads();

    const ushort_t* bwave = packW + (size_t)w*(9*4*512) + (size_t)lane*8;

    for (int t = 0; t < 16; ++t){
      if (is_enc){
        if (tid < 64)
          *(uint2*)&Ap[((tid>>4)*9 + 8)*512 + (tid&15)*8] = *(const uint2*)&xs[tid*64 + t*4];
        __syncthreads();
      }

      // ---- gate GEMM: [64,288] x [288,1024]; wave covers 4 m-tiles x 4 gate-tiles ----
      f32x4 acc[4][4];
      #pragma unroll
      for (int i = 0; i < 4; ++i)
        #pragma unroll
        for (int j = 0; j < 4; ++j) acc[i][j] = zero4;

      const ushort_t* bp = bwave;
      #pragma unroll 1
      for (int kt = 0; kt < 9; ++kt){
        bf16x8 a0 = *(const bf16x8*)&Ap[(0*9+kt)*512 + lane*8];
        bf16x8 a1 = *(const bf16x8*)&Ap[(1*9+kt)*512 + lane*8];
        bf16x8 a2 = *(const bf16x8*)&Ap[(2*9+kt)*512 + lane*8];
        bf16x8 a3 = *(const bf16x8*)&Ap[(3*9+kt)*512 + lane*8];
        #pragma unroll
        for (int g = 0; g < 4; ++g){
          bf16x8 bv = *(const bf16x8*)&bp[g*512];
          acc[0][g] = __builtin_amdgcn_mfma_f32_16x16x32_bf16(a0, bv, acc[0][g], 0, 0, 0);
          acc[1][g] = __builtin_amdgcn_mfma_f32_16x16x32_bf16(a1, bv, acc[1][g], 0, 0, 0);
          acc[2][g] = __builtin_amdgcn_mfma_f32_16x16x32_bf16(a2, bv, acc[2][g], 0, 0, 0);
          acc[3][g] = __builtin_amdgcn_mfma_f32_16x16x32_bf16(a3, bv, acc[3][g], 0, 0, 0);
        }
        bp += 4*512;
      }
      __syncthreads();   // all A reads done; safe to overwrite h

      // ---- gate nonlinearity + state update (gates share C-layout in-lane) ----
      const bool enc_last = is_enc && (t == 15);
      #pragma unroll
      for (int mt = 0; mt < 4; ++mt){
        #pragma unroll
        for (int r = 0; r < 4; ++r){
          float gi = acc[mt][0][r];
          float gf = acc[mt][1][r];
          float gg = acc[mt][2][r];
          float go = acc[mt][3][r];
          float cn = sigmf_(gf)*cw[mt][r] + sigmf_(gi)*tanhf_(gg);
          float hn = sigmf_(go)*tanhf_(cn);
          cw[mt][r] = cn;
          const int m = mt*16 + quad*4 + r;
          if (enc_last){
            if (phase == 0){ h0s[m*256+colw] = f2bf(hn);  c0s[m*256+colw] = cn; }
            else { h0s[m*256+colw] = f2bf(bf2f(h0s[m*256+colw]) + hn);  c0s[m*256+colw] += cn; }
          } else {
            Ap[mt*(9*512) + apw + (m&15)*8] = f2bf(hn);
          }
        }
      }

      if (!is_enc){
        __syncthreads();   // h_t visible for head
        if (w < 4){        // wave w handles m-tile w; kt=8 folds bias (x rows are 0 in head B)
          f32x4 hacc = zero4;
          #pragma unroll
          for (int kt = 0; kt < 9; ++kt){
            bf16x8 a  = *(const bf16x8*)&Ap[(w*9+kt)*512 + lane*8];
            bf16x8 bv = *(const bf16x8*)&headW[((size_t)kt*64 + lane)*8];
            hacc = __builtin_amdgcn_mfma_f32_16x16x32_bf16(a, bv, hacc, 0, 0, 0);
          }
          const int s = col16;
          if (phase == 2){
            if (s < 4){
              #pragma unroll
              for (int r = 0; r < 4; ++r){
                float v = fminf(fmaxf(hacc[r], -100.f), 100.f);   // hardtanh(+-100)
                const int m = w*16 + quad*4 + r;
                ost[m*64 + t*4 + s] = v;                           // staged speed output
                Ap[(w*9+8)*512 + (m&15)*8 + s] = f2bf(v);          // feedback x_{t+1}
              }
            }
          } else {
            #pragma unroll
            for (int r = 0; r < 4; ++r){
              float v = fmaxf(hacc[r], 0.f);          // relu
              const float o = __shfl_xor(v, 1, 64);   // pair lanes 4<->5 (logits)
              const int m = w*16 + quad*4 + r;
              if (s < 4){
                Ap[(w*9+8)*512 + (m&15)*8 + s] = f2bf(v);          // feedback relu(emb)
              } else if (s < 6){
                const float mx = fmaxf(v, o);
                const float e0 = __expf(v-mx), e1 = __expf(o-mx);
                ost[m*32 + t*2 + (s-4)] = e0*rcp_(e0+e1);          // staged softmax2
              }
            }
          }
        }
        __syncthreads();   // feedback x + ost visible
      }
    }

    // ---- coalesced output flush at decoder phase end ----
    if (phase == 2){
      for (int i = tid; i < 4096; i += 1024){
        const int oi = (brow0 + (i>>6))*64 + (i&63);
        const float v = ost[i];
        if (f32) outf[oi] = v; else outu[oi] = f2bf(v);
      }
    } else if (phase == 3){
      for (int i = tid; i < 2048; i += 1024){
        const int oi = 1048576 + (brow0 + (i>>5))*32 + (i&31);
        const float v = ost[i];
        if (f32) outf[oi] = v; else outu[oi] = f2bf(v);
      }
    }
  }
}

extern "C" void kernel_launch(void* const* d_in, const int* in_sizes, int n_in,
                              void* d_out, int out_size, void* d_ws, size_t ws_size,
                              hipStream_t stream) {
  PackArgs pa;
  pa.wih[0]=(const ushort_t*)d_in[2];  pa.whh[0]=(const ushort_t*)d_in[3];
  pa.bih[0]=(const ushort_t*)d_in[4];  pa.bhh[0]=(const ushort_t*)d_in[5];
  pa.wih[1]=(const ushort_t*)d_in[6];  pa.whh[1]=(const ushort_t*)d_in[7];
  pa.bih[1]=(const ushort_t*)d_in[8];  pa.bhh[1]=(const ushort_t*)d_in[9];
  pa.wih[2]=(const ushort_t*)d_in[10]; pa.whh[2]=(const ushort_t*)d_in[11];
  pa.bih[2]=(const ushort_t*)d_in[12]; pa.bhh[2]=(const ushort_t*)d_in[13];
  pa.wih[3]=(const ushort_t*)d_in[14]; pa.whh[3]=(const ushort_t*)d_in[15];
  pa.bih[3]=(const ushort_t*)d_in[16]; pa.bhh[3]=(const ushort_t*)d_in[17];
  pa.fcsp_w=(const ushort_t*)d_in[18]; pa.fcsp_b=(const ushort_t*)d_in[19];
  pa.fccr_w=(const ushort_t*)d_in[20]; pa.fccr_b=(const ushort_t*)d_in[21];
  pa.emb_w =(const ushort_t*)d_in[22]; pa.emb_b =(const ushort_t*)d_in[23];
  pa.ws = (ushort_t*)d_ws;

  hipLaunchKernelGGL(pack_kernel, dim3((PACK_TOTAL + 255)/256), dim3(256), 0, stream, pa);
  hipLaunchKernelGGL(pvlstm_main, dim3(256), dim3(1024), 0, stream,
      (const ushort_t*)d_ws,
      (const ushort_t*)d_in[0], (const ushort_t*)d_in[1],
      d_out);
}

// Round 6
// 920.353 us; speedup vs baseline: 2.4355x; 1.0942x over previous
//
#include <hip/hip_runtime.h>

typedef unsigned short ushort_t;
typedef __bf16 bf16x8 __attribute__((ext_vector_type(8)));
typedef float f32x4 __attribute__((ext_vector_type(4)));

#define PACK_W_ELEMS (8*9*8*512)           // 294912 bf16 per LSTM: [wave8][kt9][gu8][512]
#define HEAD_ELEMS   (9*512)               // 1 n-tile x 9 k-tiles
#define PACK_TOTAL   (4*PACK_W_ELEMS + 2*HEAD_ELEMS)
#define FLAG_OFS     PACK_TOTAL            // ushort index of int dtype flag

__device__ __forceinline__ float bf2f(ushort_t u){ return __uint_as_float(((unsigned)u)<<16); }
__device__ __forceinline__ ushort_t f2bf(float f){
  __bf16 h = (__bf16)f;                    // HW RTNE convert (values bounded)
  return *(ushort_t*)&h;
}
__device__ __forceinline__ float rcp_(float x){ return __builtin_amdgcn_rcpf(x); }
__device__ __forceinline__ float sigmf_(float x){ return rcp_(1.0f + __expf(-x)); }
__device__ __forceinline__ float tanhf_(float x){ return 1.0f - 2.0f*rcp_(1.0f + __expf(2.0f*x)); }

__device__ __forceinline__ int sniff_f32(const ushort_t* w){
  int f32 = 0;
  #pragma unroll
  for (int i = 0; i < 32; ++i){
    float f = bf2f(w[2*i]);
    if (!(f > -8.f && f < 8.f)) f32 = 1;
  }
  return f32;
}
__device__ __forceinline__ float ldin(const ushort_t* p, int i, int f32){
  return f32 ? ((const float*)p)[i] : bf2f(p[i]);
}
__device__ __forceinline__ ushort_t ldw(const ushort_t* p, int i, int f32){
  return f32 ? f2bf(((const float*)p)[i]) : p[i];
}

// ---------------- pack kernel ----------------
// Per-LSTM pack: [wv(8)][kt(9)][gu(8)][512]; tile (wv,kt,g,u) = B-frag of n-tile
// ntg = g*16 + wv*2 + u.  K map: k<256 Whh, 256..259 Wih, k==260 bias row (bih+bhh), else 0.
struct PackArgs {
  const ushort_t* wih[4]; const ushort_t* whh[4];
  const ushort_t* bih[4]; const ushort_t* bhh[4];
  const ushort_t* fcsp_w; const ushort_t* fcsp_b;
  const ushort_t* fccr_w; const ushort_t* fccr_b;
  const ushort_t* emb_w;  const ushort_t* emb_b;
  ushort_t* ws;
};

__global__ void pack_kernel(PackArgs a){
  const int f32 = sniff_f32(a.whh[0]);
  int idx = blockIdx.x*256 + threadIdx.x;
  if (blockIdx.x == 0 && threadIdx.x == 0) *(int*)(a.ws + FLAG_OFS) = f32;
  const int total_w = 4*PACK_W_ELEMS;
  if (idx < total_w){
    int l = idx / PACK_W_ELEMS;
    int r = idx % PACK_W_ELEMS;
    int j = r & 7;
    int lane = (r>>3) & 63;
    int tile = r >> 9;            // (wv*9 + kt)*8 + gu
    int gu = tile & 7;
    int kt = (tile >> 3) % 9;
    int wv = tile / 72;
    int g = gu >> 1, u = gu & 1;
    int n = (g*16 + wv*2 + u)*16 + (lane & 15);
    int k = kt*32 + ((lane>>4)<<3) + j;
    ushort_t v = 0;
    if (k < 256)       v = ldw(a.whh[l], n*256 + k, f32);
    else if (k < 260)  v = ldw(a.wih[l], n*4 + (k-256), f32);
    else if (k == 260) v = f2bf(ldin(a.bih[l], n, f32) + ldin(a.bhh[l], n, f32));
    a.ws[l*PACK_W_ELEMS + r] = v;
    return;
  }
  idx -= total_w;
  if (idx < 2*HEAD_ELEMS){
    int which = idx / HEAD_ELEMS;           // 0 = speed, 1 = cross
    int r = idx % HEAD_ELEMS;
    int j = r & 7; int lane = (r>>3)&63; int kt = r>>9;
    int n = lane & 15; int k = kt*32 + ((lane>>4)<<3) + j;
    ushort_t v = 0;
    if (which == 0){
      if (n < 4){
        if (k < 256)       v = ldw(a.fcsp_w, n*256 + k, f32);
        else if (k == 260) v = f2bf(ldin(a.fcsp_b, n, f32));
      }
    } else {
      if (n < 4){
        if (k < 256)       v = ldw(a.emb_w, n*256 + k, f32);
        else if (k == 260) v = f2bf(ldin(a.emb_b, n, f32));
      } else if (n < 6){
        if (k < 256)       v = ldw(a.fccr_w, (n-4)*256 + k, f32);
        else if (k == 260) v = f2bf(ldin(a.fccr_b, n-4, f32));
      }
    }
    a.ws[total_w + idx] = v;
  }
}

// ---------------- device helpers for the main kernel ----------------
__device__ __forceinline__ void gate_gemm(const ushort_t* __restrict__ Ap,   // + lane*8
                                          const ushort_t* __restrict__ bw,  // wave pack + lane*8
                                          f32x4 (&acc)[4][8], int lane){
  #pragma unroll
  for (int i = 0; i < 4; ++i)
    #pragma unroll
    for (int j = 0; j < 8; ++j) acc[i][j] = (f32x4){0.f,0.f,0.f,0.f};
  const ushort_t* bp = bw;
  #pragma unroll 1
  for (int kt = 0; kt < 9; ++kt){
    bf16x8 a0 = *(const bf16x8*)&Ap[(0*9+kt)*512];
    bf16x8 a1 = *(const bf16x8*)&Ap[(1*9+kt)*512];
    bf16x8 a2 = *(const bf16x8*)&Ap[(2*9+kt)*512];
    bf16x8 a3 = *(const bf16x8*)&Ap[(3*9+kt)*512];
    #pragma unroll
    for (int gu = 0; gu < 8; ++gu){
      bf16x8 bv = *(const bf16x8*)&bp[gu*512];
      acc[0][gu] = __builtin_amdgcn_mfma_f32_16x16x32_bf16(a0, bv, acc[0][gu], 0, 0, 0);
      acc[1][gu] = __builtin_amdgcn_mfma_f32_16x16x32_bf16(a1, bv, acc[1][gu], 0, 0, 0);
      acc[2][gu] = __builtin_amdgcn_mfma_f32_16x16x32_bf16(a2, bv, acc[2][gu], 0, 0, 0);
      acc[3][gu] = __builtin_amdgcn_mfma_f32_16x16x32_bf16(a3, bv, acc[3][gu], 0, 0, 0);
    }
    bp += 8*512;
  }
}

// gate nonlinearity + h writeback into A-frag layout; acc idx: i->u, f->2+u, g->4+u, o->6+u
__device__ __forceinline__ void gates_wb(f32x4 (&acc)[4][8], float (&cw)[4][2][4],
                                         ushort_t* __restrict__ Ap, int wbBase){
  #pragma unroll
  for (int mt = 0; mt < 4; ++mt)
    #pragma unroll
    for (int u = 0; u < 2; ++u)
      #pragma unroll
      for (int r = 0; r < 4; ++r){
        float cn = sigmf_(acc[mt][2+u][r])*cw[mt][u][r]
                 + sigmf_(acc[mt][u][r])*tanhf_(acc[mt][4+u][r]);
        float hn = sigmf_(acc[mt][6+u][r])*tanhf_(cn);
        cw[mt][u][r] = cn;
        Ap[mt*4608 + u*256 + r*8 + wbBase] = f2bf(hn);
      }
}

// ---------------- main kernel: 256 blocks x 64 rows, 512 threads (8 waves) ----------------
// Wave w owns h-cols [w*32, w*32+32) of all 4 gates, all 4 m-tiles (acc 128 AGPR).
// Merged-pair schedule: each barrier region runs one LSTM's GEMM alongside the other
// LSTM's gate-VALU + writeback, overlapping L2/LDS streams with transcendental math.
__global__ __launch_bounds__(512, 2) void pvlstm_main(
    const ushort_t* __restrict__ ws,
    const ushort_t* __restrict__ speed,
    const ushort_t* __restrict__ pos,
    void* __restrict__ outv)
{
  __shared__ ushort_t ApS[4*9*512];   // A-pack speed-enc / speed-dec (36 KB)
  __shared__ ushort_t ApP[4*9*512];   // A-pack pos-enc / cross-dec   (36 KB)
  __shared__ ushort_t xsS[64*64];     // staged speed inputs (8 KB)
  __shared__ ushort_t xsP[64*64];     // staged pos inputs   (8 KB)
  __shared__ float    ostS[64*64];    // speed outputs stage (16 KB)
  __shared__ float    ostC[64*32];    // crossing outputs stage (8 KB)

  const int f32   = *(const int*)(ws + FLAG_OFS);
  const int tid   = threadIdx.x;
  const int lane  = tid & 63;
  const int w     = tid >> 6;   // 0..7
  const int col16 = lane & 15;
  const int quad  = lane >> 4;
  const int brow0 = blockIdx.x * 64;
  const int wbBase = w*512 + (col16>>3)*128 + quad*32 + (col16&7);

  ushort_t* outu = (ushort_t*)outv;
  float*    outf = (float*)outv;

  const ushort_t* headsp = ws + 4*PACK_W_ELEMS;
  const ushort_t* headcr = headsp + HEAD_ELEMS;
  const ushort_t* aS  = ApS + lane*8;
  const ushort_t* aP  = ApP + lane*8;
  const ushort_t* bwS  = ws + 0*PACK_W_ELEMS + (size_t)w*36864 + (size_t)lane*8;
  const ushort_t* bwP  = ws + 1*PACK_W_ELEMS + (size_t)w*36864 + (size_t)lane*8;
  const ushort_t* bwDS = ws + 2*PACK_W_ELEMS + (size_t)w*36864 + (size_t)lane*8;
  const ushort_t* bwDC = ws + 3*PACK_W_ELEMS + (size_t)w*36864 + (size_t)lane*8;

  float cwA[4][2][4], cwB[4][2][4];
  f32x4 acc[4][8];

  // ---- prologue: stage inputs, zero A-packs, bias column, x_sp(0) ----
  for (int i = tid; i < 4096; i += 512){
    int gi = (brow0 + (i>>6))*64 + (i&63);
    xsS[i] = f2bf(ldin(speed, gi, f32));
    xsP[i] = f2bf(ldin(pos,   gi, f32));
  }
  for (int i = tid; i < 4*9*512/2; i += 512){
    ((unsigned*)ApS)[i] = 0u; ((unsigned*)ApP)[i] = 0u;
  }
  #pragma unroll
  for (int mt = 0; mt < 4; ++mt)
    #pragma unroll
    for (int u = 0; u < 2; ++u)
      #pragma unroll
      for (int r = 0; r < 4; ++r){ cwA[mt][u][r] = 0.f; cwB[mt][u][r] = 0.f; }
  __syncthreads();
  if (tid < 64){
    ushort_t* xpS = &ApS[((tid>>4)*9 + 8)*512 + (tid&15)*8];
    ushort_t* xpP = &ApP[((tid>>4)*9 + 8)*512 + (tid&15)*8];
    *(uint2*)xpS = *(const uint2*)&xsS[tid*64];    // x_sp(0)
    xpS[4] = (ushort_t)0x3f80;                     // bias 1.0 column
    xpP[4] = (ushort_t)0x3f80;
  }
  __syncthreads();

  // ================= encoders: sp (A) and po (B), interleaved =================
  for (int t = 0; t < 16; ++t){
    // R1: gates_po(t-1)+wb -> ApP ; x_po(t) -> ApP.kt8 ; GEMM_sp(t) from ApS
    if (t > 0) gates_wb(acc, cwB, ApP, wbBase);
    if (tid < 64)
      *(uint2*)&ApP[((tid>>4)*9 + 8)*512 + (tid&15)*8] = *(const uint2*)&xsP[tid*64 + t*4];
    gate_gemm(aS, bwS, acc, lane);
    __syncthreads();
    // R2: gates_sp(t)+wb -> ApS ; x_sp(t+1) -> ApS.kt8 ; GEMM_po(t) from ApP
    gates_wb(acc, cwA, ApS, wbBase);
    if (t < 15 && tid < 64)
      *(uint2*)&ApS[((tid>>4)*9 + 8)*512 + (tid&15)*8] = *(const uint2*)&xsS[tid*64 + t*4 + 4];
    gate_gemm(aP, bwP, acc, lane);
    __syncthreads();
  }
  // ---- encoder epilogue: gates_po(15); h0 = h_sp+h_po into BOTH packs; c0 in regs ----
  #pragma unroll
  for (int mt = 0; mt < 4; ++mt)
    #pragma unroll
    for (int u = 0; u < 2; ++u)
      #pragma unroll
      for (int r = 0; r < 4; ++r){
        float cn = sigmf_(acc[mt][2+u][r])*cwB[mt][u][r]
                 + sigmf_(acc[mt][u][r])*tanhf_(acc[mt][4+u][r]);
        float hn = sigmf_(acc[mt][6+u][r])*tanhf_(cn);
        float c0 = cwA[mt][u][r] + cn;
        cwA[mt][u][r] = c0; cwB[mt][u][r] = c0;
        const int ad = mt*4608 + u*256 + r*8 + wbBase;
        ushort_t h0 = f2bf(bf2f(ApS[ad]) + hn);    // own value written in R2(15)
        ApS[ad] = h0; ApP[ad] = h0;
      }
  if (tid < 64){
    *(uint2*)&ApS[((tid>>4)*9 + 8)*512 + (tid&15)*8] = *(const uint2*)&xsS[tid*64 + 60];  // x0 sp
    *(uint2*)&ApP[((tid>>4)*9 + 8)*512 + (tid&15)*8] = *(const uint2*)&xsP[tid*64 + 60];  // x0 po
  }
  __syncthreads();

  // ================= decoders: dsp (A, ApS) and dcr (B, ApP), interleaved =================
  for (int t = 0; t < 16; ++t){
    // R1: head_cr(t-1) [waves 4..7] -> ostC + x_cr(t) ; GEMM_dsp(t) from ApS
    if (t > 0 && w >= 4){
      const int mt = w - 4;
      f32x4 hacc = (f32x4){0.f,0.f,0.f,0.f};
      #pragma unroll
      for (int kt = 0; kt < 9; ++kt){
        bf16x8 a  = *(const bf16x8*)&aP[(mt*9+kt)*512];
        bf16x8 bv = *(const bf16x8*)&headcr[((size_t)kt*64 + lane)*8];
        hacc = __builtin_amdgcn_mfma_f32_16x16x32_bf16(a, bv, hacc, 0, 0, 0);
      }
      const int s = col16;
      #pragma unroll
      for (int r = 0; r < 4; ++r){
        float v = fmaxf(hacc[r], 0.f);             // relu
        const float o = __shfl_xor(v, 1, 64);      // pair logits (lanes 4<->5)
        const int m = mt*16 + quad*4 + r;
        if (s < 4){
          ApP[(mt*9+8)*512 + (m&15)*8 + s] = f2bf(v);          // x_cr(t) feedback
        } else if (s < 6){
          const float mx = fmaxf(v, o);
          const float e0 = __expf(v-mx), e1 = __expf(o-mx);
          ostC[m*32 + (t-1)*2 + (s-4)] = e0*rcp_(e0+e1);       // softmax2 at t-1
        }
      }
    }
    gate_gemm(aS, bwDS, acc, lane);
    __syncthreads();
    // R2: gates_dsp(t)+wb -> ApS ; GEMM_dcr(t) from ApP
    gates_wb(acc, cwA, ApS, wbBase);
    gate_gemm(aP, bwDC, acc, lane);
    __syncthreads();
    // R3: gates_dcr(t)+wb -> ApP ; head_sp(t) [waves 0..3] -> ostS + x_sp(t+1)
    gates_wb(acc, cwB, ApP, wbBase);
    if (w < 4){
      const int mt = w;
      f32x4 hacc = (f32x4){0.f,0.f,0.f,0.f};
      #pragma unroll
      for (int kt = 0; kt < 9; ++kt){
        bf16x8 a  = *(const bf16x8*)&aS[(mt*9+kt)*512];
        bf16x8 bv = *(const bf16x8*)&headsp[((size_t)kt*64 + lane)*8];
        hacc = __builtin_amdgcn_mfma_f32_16x16x32_bf16(a, bv, hacc, 0, 0, 0);
      }
      const int s = col16;
      if (s < 4){
        #pragma unroll
        for (int r = 0; r < 4; ++r){
          float v = fminf(fmaxf(hacc[r], -100.f), 100.f);      // hardtanh(+-100)
          const int m = mt*16 + quad*4 + r;
          ostS[m*64 + t*4 + s] = v;
          ApS[(mt*9+8)*512 + (m&15)*8 + s] = f2bf(v);          // x_sp(t+1) feedback
        }
      }
    }
    __syncthreads();
  }
  // ---- decoder epilogue: head_cr(15) ----
  if (w >= 4){
    const int mt = w - 4;
    f32x4 hacc = (f32x4){0.f,0.f,0.f,0.f};
    #pragma unroll
    for (int kt = 0; kt < 9; ++kt){
      bf16x8 a  = *(const bf16x8*)&aP[(mt*9+kt)*512];
      bf16x8 bv = *(const bf16x8*)&headcr[((size_t)kt*64 + lane)*8];
      hacc = __builtin_amdgcn_mfma_f32_16x16x32_bf16(a, bv, hacc, 0, 0, 0);
    }
    const int s = col16;
    if (s >= 4 && s < 6){
      #pragma unroll
      for (int r = 0; r < 4; ++r){
        float v = fmaxf(hacc[r], 0.f);
        const float o = __shfl_xor(v, 1, 64);
        const int m = mt*16 + quad*4 + r;
        const float mx = fmaxf(v, o);
        const float e0 = __expf(v-mx), e1 = __expf(o-mx);
        ostC[m*32 + 15*2 + (s-4)] = e0*rcp_(e0+e1);
      }
    }
  }
  __syncthreads();

  // ---- coalesced output flush ----
  for (int i = tid; i < 4096; i += 512){
    const int oi = (brow0 + (i>>6))*64 + (i&63);
    const float v = ostS[i];
    if (f32) outf[oi] = v; else outu[oi] = f2bf(v);
  }
  for (int i = tid; i < 2048; i += 512){
    const int oi = 1048576 + (brow0 + (i>>5))*32 + (i&31);
    const float v = ostC[i];
    if (f32) outf[oi] = v; else outu[oi] = f2bf(v);
  }
}

extern "C" void kernel_launch(void* const* d_in, const int* in_sizes, int n_in,
                              void* d_out, int out_size, void* d_ws, size_t ws_size,
                              hipStream_t stream) {
  PackArgs pa;
  pa.wih[0]=(const ushort_t*)d_in[2];  pa.whh[0]=(const ushort_t*)d_in[3];
  pa.bih[0]=(const ushort_t*)d_in[4];  pa.bhh[0]=(const ushort_t*)d_in[5];
  pa.wih[1]=(const ushort_t*)d_in[6];  pa.whh[1]=(const ushort_t*)d_in[7];
  pa.bih[1]=(const ushort_t*)d_in[8];  pa.bhh[1]=(const ushort_t*)d_in[9];
  pa.wih[2]=(const ushort_t*)d_in[10]; pa.whh[2]=(const ushort_t*)d_in[11];
  pa.bih[2]=(const ushort_t*)d_in[12]; pa.bhh[2]=(const ushort_t*)d_in[13];
  pa.wih[3]=(const ushort_t*)d_in[14]; pa.whh[3]=(const ushort_t*)d_in[15];
  pa.bih[3]=(const ushort_t*)d_in[16]; pa.bhh[3]=(const ushort_t*)d_in[17];
  pa.fcsp_w=(const ushort_t*)d_in[18]; pa.fcsp_b=(const ushort_t*)d_in[19];
  pa.fccr_w=(const ushort_t*)d_in[20]; pa.fccr_b=(const ushort_t*)d_in[21];
  pa.emb_w =(const ushort_t*)d_in[22]; pa.emb_b =(const ushort_t*)d_in[23];
  pa.ws = (ushort_t*)d_ws;

  hipLaunchKernelGGL(pack_kernel, dim3((PACK_TOTAL + 255)/256), dim3(256), 0, stream, pa);
  hipLaunchKernelGGL(pvlstm_main, dim3(256), dim3(512), 0, stream,
      (const ushort_t*)d_ws,
      (const ushort_t*)d_in[0], (const ushort_t*)d_in[1],
      d_out);
}